// Round 2
// baseline (3881.985 us; speedup 1.0000x reference)
//
#include <hip/hip_runtime.h>

#pragma clang fp contract(off)

#define ALPHA  0.9f
#define RHO    0.985f
#define BETA_A 1.8f
#define TH     1.0f

// ---------------------------------------------------------------------------
// Generic 32x32 tiled transpose: src[R][C] -> dst[C][R]
// ---------------------------------------------------------------------------
__global__ __launch_bounds__(256) void transpose_k(const float* __restrict__ src,
                                                   float* __restrict__ dst,
                                                   int R, int C) {
    __shared__ float tile[32][33];
    const int c0 = blockIdx.x * 32;
    const int r0 = blockIdx.y * 32;
    const int tx = threadIdx.x, ty = threadIdx.y;
#pragma unroll
    for (int i = 0; i < 4; ++i)
        tile[ty + i * 8][tx] = src[(r0 + ty + i * 8) * C + c0 + tx];
    __syncthreads();
#pragma unroll
    for (int i = 0; i < 4; ++i)
        dst[(c0 + ty + i * 8) * R + r0 + tx] = tile[tx][ty + i * 8];
}

// ---------------------------------------------------------------------------
// Input projection: out[r][n] = sum_k inp[r][k] * Wt[k][n] + bias[n]
// ---------------------------------------------------------------------------
__global__ __launch_bounds__(256) void ip_gemm(const float* __restrict__ inp,
                                               const float* __restrict__ Wt,
                                               const float* __restrict__ bias,
                                               float* __restrict__ out) {
    __shared__ __align__(16) float s_in[512 * 20];
    const int tid   = threadIdx.x;
    const int chunk = blockIdx.x;
    const int rbase = blockIdx.y * 16;

    for (int idx = tid; idx < 16 * 512; idx += 256) {
        const int r = idx >> 9, k = idx & 511;
        s_in[k * 20 + r] = inp[(rbase + r) * 512 + k];
    }
    __syncthreads();

    const int n = chunk * 256 + tid;
    float acc[16];
#pragma unroll
    for (int r = 0; r < 16; ++r) acc[r] = 0.f;

    for (int k = 0; k < 512; ++k) {
        const float w = Wt[k * 1024 + n];
        const float4* p = (const float4*)(s_in + k * 20);
        const float4 x0 = p[0], x1 = p[1], x2 = p[2], x3 = p[3];
        acc[0]  = fmaf(x0.x, w, acc[0]);  acc[1]  = fmaf(x0.y, w, acc[1]);
        acc[2]  = fmaf(x0.z, w, acc[2]);  acc[3]  = fmaf(x0.w, w, acc[3]);
        acc[4]  = fmaf(x1.x, w, acc[4]);  acc[5]  = fmaf(x1.y, w, acc[5]);
        acc[6]  = fmaf(x1.z, w, acc[6]);  acc[7]  = fmaf(x1.w, w, acc[7]);
        acc[8]  = fmaf(x2.x, w, acc[8]);  acc[9]  = fmaf(x2.y, w, acc[9]);
        acc[10] = fmaf(x2.z, w, acc[10]); acc[11] = fmaf(x2.w, w, acc[11]);
        acc[12] = fmaf(x3.x, w, acc[12]); acc[13] = fmaf(x3.y, w, acc[13]);
        acc[14] = fmaf(x3.z, w, acc[14]); acc[15] = fmaf(x3.w, w, acc[15]);
    }
    const float bn = bias[n];
#pragma unroll
    for (int r = 0; r < 16; ++r) out[(rbase + r) * 1024 + n] = acc[r] + bn;
}

// ---------------------------------------------------------------------------
// Pair-split main kernel: 256 blocks x 512 threads.
// Block (b, s) handles batch b, neuron columns [s*512, s*512+512).
// Partner blocks exchange 512-bit spike halves through d_ws with AGENT-scope
// atomics + monotonically increasing epoch flags (memset to 0 at launch).
// ---------------------------------------------------------------------------

__device__ __forceinline__ void publish_half(bool pred, int s, int wid, int lane, int tid,
                                             unsigned long long* lds_bits16,
                                             unsigned long long* gslot8,
                                             int* gflag_self, int epoch) {
    const unsigned long long m = __ballot(pred);
    if (lane == 0) {
        lds_bits16[8 * s + wid] = m;
        __hip_atomic_store(&gslot8[wid], m, __ATOMIC_RELAXED, __HIP_MEMORY_SCOPE_AGENT);
    }
    __syncthreads();
    if (tid == 0)
        __hip_atomic_store(gflag_self, epoch, __ATOMIC_RELEASE, __HIP_MEMORY_SCOPE_AGENT);
}

__device__ __forceinline__ void wait_half(int s, int tid,
                                          unsigned long long* lds_bits16,
                                          const unsigned long long* gsrc8,
                                          int* gflag_partner, int epoch) {
    if (tid == 0) {
        int guard = 0;
        while (__hip_atomic_load(gflag_partner, __ATOMIC_ACQUIRE, __HIP_MEMORY_SCOPE_AGENT) < epoch
               && ++guard < (1 << 22)) {}
    }
    __syncthreads();
    if (tid < 8)
        lds_bits16[8 * (1 - s) + tid] =
            __hip_atomic_load(&gsrc8[tid], __ATOMIC_RELAXED, __HIP_MEMORY_SCOPE_AGENT);
    __syncthreads();
}

// bits16: full 1024-bit spike map in LDS. Builds ordered index list, returns count.
__device__ __forceinline__ int build_list(const unsigned long long* bits16, int* pc,
                                          int* list, int tid) {
    if (tid < 16) pc[tid] = __popcll(bits16[tid]);
    __syncthreads();
    int total = 0;
#pragma unroll
    for (int w = 0; w < 16; ++w) total += pc[w];
    for (int j = tid; j < 1024; j += 512) {
        const int w = j >> 6, bit = j & 63;
        const unsigned long long m = bits16[w];
        if ((m >> bit) & 1ull) {
            int base = __popcll(m & ((1ull << bit) - 1ull));
            for (int x = 0; x < w; ++x) base += pc[x];
            list[base] = j;
        }
    }
    __syncthreads();
    return total;
}

template <int S>
__device__ __forceinline__ float gather1(const float* __restrict__ W,
                                         const int* __restrict__ list, int cnt, int col) {
    float a0 = 0.f, a1 = 0.f, a2 = 0.f, a3 = 0.f;
    int i = 0;
    for (; i + 4 <= cnt; i += 4) {
        const int4 j = *(const int4*)(list + i);
        a0 += W[j.x * S + col];
        a1 += W[j.y * S + col];
        a2 += W[j.z * S + col];
        a3 += W[j.w * S + col];
    }
    for (; i < cnt; ++i) a0 += W[list[i] * S + col];
    return (a0 + a1) + (a2 + a3);
}

// Fused gather over one list from two matrices (phase C uses W_post rows, the
// NEXT phase A uses W_pre rows -- same s_a spike list).
__device__ __forceinline__ void gather2(const float* __restrict__ Wc,
                                        const float* __restrict__ Wa,
                                        const int* __restrict__ list, int cnt, int col,
                                        float& accC, float& accA) {
    float c0 = 0.f, c1 = 0.f, a0 = 0.f, a1 = 0.f;
    int i = 0;
    for (; i + 2 <= cnt; i += 2) {
        const int2 j = *(const int2*)(list + i);
        c0 += Wc[j.x * 1024 + col];
        a0 += Wa[j.x * 1024 + col];
        c1 += Wc[j.y * 1024 + col];
        a1 += Wa[j.y * 1024 + col];
    }
    if (i < cnt) {
        const int j = list[i];
        c0 += Wc[j * 1024 + col];
        a0 += Wa[j * 1024 + col];
    }
    accC = c0 + c1;
    accA = a0 + a1;
}

__global__ __launch_bounds__(512) void rsnn_main2(
    const float* __restrict__ Wt_pre,   // [1536][1024]
    const float* __restrict__ Wt_ad,    // [1024][1024]
    const float* __restrict__ Wt_post,  // [1536][1024]
    const float* __restrict__ Wt_out,   // [1024][256]
    const float* __restrict__ IP_pre,   // [4096][1024]
    const float* __restrict__ IP_post,  // [4096][1024]
    const float* __restrict__ b_ad_p,   // [1024]
    const float* __restrict__ b_out_p,  // [256]
    unsigned long long* __restrict__ bitsE1,  // [128][2][8]
    unsigned long long* __restrict__ bitsE2,  // [128][2][8]
    unsigned long long* __restrict__ bitsE3,  // [128][8]
    int* __restrict__ flagE1,                 // [128][2]
    int* __restrict__ flagE2,                 // [128][2]
    int* __restrict__ flagE3,                 // [128]
    float* __restrict__ out)
{
    const int tid  = threadIdx.x;
    const int b    = blockIdx.x & 127;
    const int s    = blockIdx.x >> 7;
    const int wid  = tid >> 6;
    const int lane = tid & 63;
    const int col  = s * 512 + tid;

    __shared__ unsigned long long bits[16];
    __shared__ int pc[16];
    __shared__ __align__(16) int listB[1024];
    __shared__ __align__(16) int listA[1024];

    unsigned long long* myE1   = bitsE1 + (b * 2 + s) * 8;
    unsigned long long* prtE1  = bitsE1 + (b * 2 + (1 - s)) * 8;
    unsigned long long* myE2   = bitsE2 + (b * 2 + s) * 8;
    unsigned long long* prtE2  = bitsE2 + (b * 2 + (1 - s)) * 8;
    int* myF1  = flagE1 + b * 2 + s;
    int* prtF1 = flagE1 + b * 2 + (1 - s);
    int* myF2  = flagE2 + b * 2 + s;
    int* prtF2 = flagE2 + b * 2 + (1 - s);

    float v_pre = 0.f, v_a = 0.f, ba = 0.f, v_post = 0.f, accA = 0.f;
    const float bad  = b_ad_p[col];
    const float bout = (s == 0 && tid < 256) ? b_out_p[tid] : 0.f;
    const float* WpreA  = Wt_pre  + 512 * 1024;
    const float* WpostA = Wt_post + 512 * 1024;

    bool sa = false;

    for (int t = 0; t < 32; ++t) {
        const int row = t * 128 + b;
        const float ipre  = IP_pre [row * 1024 + col];
        const float ipost = IP_post[row * 1024 + col];
        for (int k = 0; k < 3; ++k) {
            const int ep = t * 3 + k + 1;

            // ---- A: v_pre update (spike-gather term was precomputed) ----
            v_pre = ALPHA * v_pre + ipre + accA;
            float d = v_pre - TH;
            const bool sp = d > 0.f;
            if (sp) v_pre = d;
            publish_half(sp, s, wid, lane, tid, bits, myE1, myF1, ep);
            wait_half(s, tid, bits, prtE1, prtF1, ep);
            const int cntB = build_list(bits, pc, listB, tid);

            // ---- B: v_a update, adaptive threshold ----
            const float accB = gather1<1024>(Wt_ad, listB, cntB, col);
            v_a = ALPHA * v_a + accB + bad;
            const float th = TH + BETA_A * ba;
            d = v_a - th;
            sa = d > 0.f;
            if (sa) v_a = d;
            ba = RHO * ba + (sa ? 1.f : 0.f);
            publish_half(sa, s, wid, lane, tid, bits, myE2, myF2, ep);
            wait_half(s, tid, bits, prtE2, prtF2, ep);
            const int cntA = build_list(bits, pc, listA, tid);

            // ---- C (+ next A's gather, same s_a list) ----
            float accC;
            gather2(WpostA, WpreA, listA, cntA, col, accC, accA);
            v_post = ALPHA * v_post + ipost + accC;
            d = v_post - TH;
            const bool spost = d > 0.f;
            if (spost) v_post = d;

            if (k == 2) {
                const unsigned long long m = __ballot(spost);
                if (s == 1) {
                    if (lane == 0)
                        __hip_atomic_store(&bitsE3[b * 8 + wid], m, __ATOMIC_RELAXED,
                                           __HIP_MEMORY_SCOPE_AGENT);
                    __syncthreads();
                    if (tid == 0)
                        __hip_atomic_store(&flagE3[b], t + 1, __ATOMIC_RELEASE,
                                           __HIP_MEMORY_SCOPE_AGENT);
                } else {
                    if (lane == 0) bits[wid] = m;
                    __syncthreads();
                    if (tid == 0) {
                        int guard = 0;
                        while (__hip_atomic_load(&flagE3[b], __ATOMIC_ACQUIRE,
                                                 __HIP_MEMORY_SCOPE_AGENT) < t + 1
                               && ++guard < (1 << 22)) {}
                    }
                    __syncthreads();
                    if (tid < 8)
                        bits[8 + tid] = __hip_atomic_load(&bitsE3[b * 8 + tid], __ATOMIC_RELAXED,
                                                          __HIP_MEMORY_SCOPE_AGENT);
                    __syncthreads();
                    const int cntC = build_list(bits, pc, listB, tid);
                    if (tid < 256) {
                        const float o = gather1<256>(Wt_out, listB, cntC, tid);
                        out[row * 256 + tid] = o + bout;
                    }
                }
                if (t == 31)
                    out[32 * 128 * 256 + b * 1024 + col] = sa ? 1.f : 0.f;
            }
        }
    }
}

// ---------------------------------------------------------------------------
extern "C" void kernel_launch(void* const* d_in, const int* in_sizes, int n_in,
                              void* d_out, int out_size, void* d_ws, size_t ws_size,
                              hipStream_t stream) {
    (void)in_sizes; (void)n_in; (void)out_size; (void)ws_size;
    const float* inp    = (const float*)d_in[0];
    const float* W_pre  = (const float*)d_in[1];
    const float* b_pre  = (const float*)d_in[2];
    const float* W_ad   = (const float*)d_in[3];
    const float* b_ad   = (const float*)d_in[4];
    const float* W_post = (const float*)d_in[5];
    const float* b_post = (const float*)d_in[6];
    const float* W_out  = (const float*)d_in[7];
    const float* b_out  = (const float*)d_in[8];

    // ws layout: [flags | bits | weights/IP]
    char* base = (char*)d_ws;
    int*  flagE1 = (int*)base;                       // 256 ints
    int*  flagE2 = flagE1 + 256;                     // 256 ints
    int*  flagE3 = flagE2 + 256;                     // 128 ints
    unsigned long long* bitsE1 = (unsigned long long*)(base + 4096);   // 2048 u64
    unsigned long long* bitsE2 = bitsE1 + 2048;                        // 2048 u64
    unsigned long long* bitsE3 = bitsE2 + 2048;                        // 1024 u64
    float* ws      = (float*)(base + 65536);
    float* Wt_pre  = ws;
    float* Wt_post = Wt_pre  + 1536 * 1024;
    float* Wt_ad   = Wt_post + 1536 * 1024;
    float* Wt_out  = Wt_ad   + 1024 * 1024;
    float* IP_pre  = Wt_out  + 1024 * 256;
    float* IP_post = IP_pre  + 4096 * 1024;

    hipMemsetAsync(base, 0, 4096, stream);  // zero epoch flags each launch

    transpose_k<<<dim3(48, 32), dim3(32, 8), 0, stream>>>(W_pre,  Wt_pre,  1024, 1536);
    transpose_k<<<dim3(48, 32), dim3(32, 8), 0, stream>>>(W_post, Wt_post, 1024, 1536);
    transpose_k<<<dim3(32, 32), dim3(32, 8), 0, stream>>>(W_ad,   Wt_ad,   1024, 1024);
    transpose_k<<<dim3(32, 8),  dim3(32, 8), 0, stream>>>(W_out,  Wt_out,  256,  1024);

    ip_gemm<<<dim3(4, 256), 256, 0, stream>>>(inp, Wt_pre,  b_pre,  IP_pre);
    ip_gemm<<<dim3(4, 256), 256, 0, stream>>>(inp, Wt_post, b_post, IP_post);

    rsnn_main2<<<256, 512, 0, stream>>>(Wt_pre, Wt_ad, Wt_post, Wt_out,
                                        IP_pre, IP_post, b_ad, b_out,
                                        bitsE1, bitsE2, bitsE3,
                                        flagE1, flagE2, flagE3,
                                        (float*)d_out);
}

// Round 3
// 1921.526 us; speedup vs baseline: 2.0203x; 2.0203x over previous
//
#include <hip/hip_runtime.h>

#pragma clang fp contract(off)

typedef unsigned long long u64;

#define ALPHA  0.9f
#define RHO    0.985f
#define BETA_A 1.8f
#define TH     1.0f

// ---------------------------------------------------------------------------
// Generic 32x32 tiled transpose: src[R][C] -> dst[C][R]
// ---------------------------------------------------------------------------
__global__ __launch_bounds__(256) void transpose_k(const float* __restrict__ src,
                                                   float* __restrict__ dst,
                                                   int R, int C) {
    __shared__ float tile[32][33];
    const int c0 = blockIdx.x * 32;
    const int r0 = blockIdx.y * 32;
    const int tx = threadIdx.x, ty = threadIdx.y;
#pragma unroll
    for (int i = 0; i < 4; ++i)
        tile[ty + i * 8][tx] = src[(r0 + ty + i * 8) * C + c0 + tx];
    __syncthreads();
#pragma unroll
    for (int i = 0; i < 4; ++i)
        dst[(c0 + ty + i * 8) * R + r0 + tx] = tile[tx][ty + i * 8];
}

// ---------------------------------------------------------------------------
// Input projection: out[r][n] = sum_k inp[r][k] * Wt[k][n] + bias[n]
// ---------------------------------------------------------------------------
__global__ __launch_bounds__(256) void ip_gemm(const float* __restrict__ inp,
                                               const float* __restrict__ Wt,
                                               const float* __restrict__ bias,
                                               float* __restrict__ out) {
    __shared__ __align__(16) float s_in[512 * 20];
    const int tid   = threadIdx.x;
    const int chunk = blockIdx.x;
    const int rbase = blockIdx.y * 16;

    for (int idx = tid; idx < 16 * 512; idx += 256) {
        const int r = idx >> 9, k = idx & 511;
        s_in[k * 20 + r] = inp[(rbase + r) * 512 + k];
    }
    __syncthreads();

    const int n = chunk * 256 + tid;
    float acc[16];
#pragma unroll
    for (int r = 0; r < 16; ++r) acc[r] = 0.f;

    for (int k = 0; k < 512; ++k) {
        const float w = Wt[k * 1024 + n];
        const float4* p = (const float4*)(s_in + k * 20);
        const float4 x0 = p[0], x1 = p[1], x2 = p[2], x3 = p[3];
        acc[0]  = fmaf(x0.x, w, acc[0]);  acc[1]  = fmaf(x0.y, w, acc[1]);
        acc[2]  = fmaf(x0.z, w, acc[2]);  acc[3]  = fmaf(x0.w, w, acc[3]);
        acc[4]  = fmaf(x1.x, w, acc[4]);  acc[5]  = fmaf(x1.y, w, acc[5]);
        acc[6]  = fmaf(x1.z, w, acc[6]);  acc[7]  = fmaf(x1.w, w, acc[7]);
        acc[8]  = fmaf(x2.x, w, acc[8]);  acc[9]  = fmaf(x2.y, w, acc[9]);
        acc[10] = fmaf(x2.z, w, acc[10]); acc[11] = fmaf(x2.w, w, acc[11]);
        acc[12] = fmaf(x3.x, w, acc[12]); acc[13] = fmaf(x3.y, w, acc[13]);
        acc[14] = fmaf(x3.z, w, acc[14]); acc[15] = fmaf(x3.w, w, acc[15]);
    }
    const float bn = bias[n];
#pragma unroll
    for (int r = 0; r < 16; ++r) out[(rbase + r) * 1024 + n] = acc[r] + bn;
}

// ---------------------------------------------------------------------------
// Agent-scope relaxed helpers (write-through to coherence point; no cache
// invalidation anywhere -- this was round 2's performance bug).
// ---------------------------------------------------------------------------
__device__ __forceinline__ u64 ld_u64(const u64* p) {
    return __hip_atomic_load(p, __ATOMIC_RELAXED, __HIP_MEMORY_SCOPE_AGENT);
}
__device__ __forceinline__ void st_u64(u64* p, u64 v) {
    __hip_atomic_store(p, v, __ATOMIC_RELAXED, __HIP_MEMORY_SCOPE_AGENT);
}

// Two-level grid barrier, 256 blocks, epoch-monotonic, relaxed-only.
// Visibility argument: __syncthreads() makes the compiler emit
// s_waitcnt vmcnt(0) in every wave before s_barrier, so all of this block's
// agent-scope (write-through) stores are at the coherence point before the
// rep thread arrives. Polling is RELAXED: agent-scope loads read the
// coherence point, so no acquire/invalidate is needed.
__device__ __forceinline__ void gbar(int e, int x, int tid,
                                     int* xcd_ctr, int* root_ctr, int* epoch) {
    __syncthreads();
    if (tid == 0) {
        const int r = __hip_atomic_fetch_add(&xcd_ctr[x * 32], 1,
                                             __ATOMIC_RELAXED, __HIP_MEMORY_SCOPE_AGENT);
        if (r == 32 * e - 1) {
            const int r2 = __hip_atomic_fetch_add(root_ctr, 1,
                                                  __ATOMIC_RELAXED, __HIP_MEMORY_SCOPE_AGENT);
            if (r2 == 8 * e - 1)
                __hip_atomic_store(epoch, e, __ATOMIC_RELAXED, __HIP_MEMORY_SCOPE_AGENT);
        }
        int guard = 0;
        while (__hip_atomic_load(epoch, __ATOMIC_RELAXED, __HIP_MEMORY_SCOPE_AGENT) < e &&
               ++guard < (1 << 24)) {}
    }
    __syncthreads();
}

// Build ordered index list from a 1024-bit map; every thread returns total.
template <int T>
__device__ __forceinline__ int build_one(const u64* bmp16, const int* pc16,
                                         int* list, int tid) {
    int total = 0;
#pragma unroll
    for (int w = 0; w < 16; ++w) total += pc16[w];
    for (int j = tid; j < 1024; j += T) {
        const int w = j >> 6, bit = j & 63;
        const u64 m = bmp16[w];
        if ((m >> bit) & 1ull) {
            int base = __popcll(m & ((1ull << bit) - 1ull));
            for (int q = 0; q < w; ++q) base += pc16[q];
            list[base] = j;
        }
    }
    return total;
}

template <int S>
__device__ __forceinline__ float gather1(const float* __restrict__ W,
                                         const int* __restrict__ list, int cnt, int col) {
    float a0 = 0.f, a1 = 0.f, a2 = 0.f, a3 = 0.f;
    int i = 0;
    for (; i + 4 <= cnt; i += 4) {
        const int4 j = *(const int4*)(list + i);
        a0 += W[j.x * S + col];
        a1 += W[j.y * S + col];
        a2 += W[j.z * S + col];
        a3 += W[j.w * S + col];
    }
    for (; i < cnt; ++i) a0 += W[list[i] * S + col];
    return (a0 + a1) + (a2 + a3);
}

__device__ __forceinline__ void gather2(const float* __restrict__ Wc,
                                        const float* __restrict__ Wa,
                                        const int* __restrict__ list, int cnt, int col,
                                        float& accC, float& accA) {
    float c0 = 0.f, c1 = 0.f, a0 = 0.f, a1 = 0.f;
    int i = 0;
    for (; i + 2 <= cnt; i += 2) {
        const int2 j = *(const int2*)(list + i);
        c0 += Wc[j.x * 1024 + col];
        a0 += Wa[j.x * 1024 + col];
        c1 += Wc[j.y * 1024 + col];
        a1 += Wa[j.y * 1024 + col];
    }
    if (i < cnt) {
        const int j = list[i];
        c0 += Wc[j * 1024 + col];
        a0 += Wa[j * 1024 + col];
    }
    accC = c0 + c1;
    accA = a0 + a1;
}

// ---------------------------------------------------------------------------
// Batch-shared main kernel: 256 blocks x 512 threads.
// bid = g*8 + x; x (presumed XCD) -> column slice s = x>>1 (256 cols);
// batch pair p = 2*g + (x&1); thread -> (bi = tid>>8, col = s*256 + (tid&255)).
// Per phase: A-update -> publish s_pre -> barrier -> B gather (Wad slice)
// -> publish s_a -> barrier -> C+nextA fused gather (Wpost+Wpre slices).
// s_post bitmaps are dumped (no barrier); final out_gemm kernel consumes them.
// ---------------------------------------------------------------------------
__global__ __launch_bounds__(512) void rsnn_shared(
    const float* __restrict__ Wt_pre,   // [1536][1024]
    const float* __restrict__ Wt_ad,    // [1024][1024]
    const float* __restrict__ Wt_post,  // [1536][1024]
    const float* __restrict__ IP_pre,   // [4096][1024]
    const float* __restrict__ IP_post,  // [4096][1024]
    const float* __restrict__ b_ad_p,   // [1024]
    u64* __restrict__ spkP,             // [128][16]
    u64* __restrict__ spkS,             // [128][16]
    u64* __restrict__ spkO,             // [4096][16]
    int* __restrict__ xcd_ctr,          // 8 padded counters
    int* __restrict__ root_ctr,
    int* __restrict__ epoch,
    float* __restrict__ out)
{
    const int tid  = threadIdx.x;
    const int bid  = blockIdx.x;
    const int x    = bid & 7;
    const int g    = bid >> 3;
    const int s    = x >> 1;
    const int p    = g * 2 + (x & 1);
    const int bi   = tid >> 8;
    const int col  = s * 256 + (tid & 255);
    const int b    = 2 * p + bi;          // this thread's batch
    const int wid  = tid >> 6;
    const int lane = tid & 63;
    const int wrd  = s * 4 + (wid & 3);   // u64 word index this wave publishes

    __shared__ u64 bmp[2][16];
    __shared__ int pc[2][16];
    __shared__ __align__(16) int listP[2][1024];
    __shared__ __align__(16) int listS[2][1024];

    float v_pre = 0.f, v_a = 0.f, ba = 0.f, v_post = 0.f, accA = 0.f;
    bool  sa = false;
    const float bad = b_ad_p[col];
    const float* WpreA  = Wt_pre  + 512 * 1024;
    const float* WpostA = Wt_post + 512 * 1024;

    int ep = 0;

    for (int t = 0; t < 32; ++t) {
        const int row = t * 128 + b;
        const float ipre  = IP_pre [row * 1024 + col];
        const float ipost = IP_post[row * 1024 + col];
        for (int k = 0; k < 3; ++k) {
            // ---- A: v_pre update (spike gather precomputed in prev C) ----
            v_pre = ALPHA * v_pre + ipre + accA;
            float d = v_pre - TH;
            const bool sp = d > 0.f;
            if (sp) v_pre = d;
            {
                const u64 m = __ballot(sp);
                if (lane == 0) st_u64(&spkP[b * 16 + wrd], m);
            }
            ++ep;
            gbar(ep, x, tid, xcd_ctr, root_ctr, epoch);

            if (tid < 32) {
                const int bb = tid >> 4, w = tid & 15;
                const u64 m = ld_u64(&spkP[(2 * p + bb) * 16 + w]);
                bmp[bb][w] = m;
                pc[bb][w]  = __popcll(m);
            }
            __syncthreads();
            const int cP0 = build_one<512>(bmp[0], pc[0], listP[0], tid);
            const int cP1 = build_one<512>(bmp[1], pc[1], listP[1], tid);
            __syncthreads();

            // ---- B: v_a update, adaptive threshold ----
            const int* lp = bi ? listP[1] : listP[0];
            const int  cp = bi ? cP1 : cP0;
            const float accB = gather1<1024>(Wt_ad, lp, cp, col);
            v_a = ALPHA * v_a + accB + bad;
            const float th = TH + BETA_A * ba;
            d = v_a - th;
            sa = d > 0.f;
            if (sa) v_a = d;
            ba = RHO * ba + (sa ? 1.f : 0.f);
            {
                const u64 m = __ballot(sa);
                if (lane == 0) st_u64(&spkS[b * 16 + wrd], m);
            }
            ++ep;
            gbar(ep, x, tid, xcd_ctr, root_ctr, epoch);

            if (tid < 32) {
                const int bb = tid >> 4, w = tid & 15;
                const u64 m = ld_u64(&spkS[(2 * p + bb) * 16 + w]);
                bmp[bb][w] = m;
                pc[bb][w]  = __popcll(m);
            }
            __syncthreads();
            const int cS0 = build_one<512>(bmp[0], pc[0], listS[0], tid);
            const int cS1 = build_one<512>(bmp[1], pc[1], listS[1], tid);
            __syncthreads();

            // ---- C (+ next A's gather, same s_a list) ----
            const int* ls = bi ? listS[1] : listS[0];
            const int  cs = bi ? cS1 : cS0;
            float accC;
            gather2(WpostA, WpreA, ls, cs, col, accC, accA);
            v_post = ALPHA * v_post + ipost + accC;
            d = v_post - TH;
            const bool spost = d > 0.f;
            if (spost) v_post = d;

            if (k == 2) {
                const u64 m = __ballot(spost);
                if (lane == 0) st_u64(&spkO[row * 16 + wrd], m);
                if (t == 31)
                    out[32 * 128 * 256 + b * 1024 + col] = sa ? 1.f : 0.f;
            }
        }
    }
}

// ---------------------------------------------------------------------------
// Final output GEMM: o[r] = s_post[r] @ W_out.T + b_out, from spkO bitmaps.
// ---------------------------------------------------------------------------
__global__ __launch_bounds__(256) void out_gemm(const float* __restrict__ Wt_out, // [1024][256]
                                                const float* __restrict__ b_out,
                                                const u64* __restrict__ spkO,
                                                float* __restrict__ out) {
    __shared__ u64 bmp[16];
    __shared__ int pc[16];
    __shared__ __align__(16) int list[1024];
    const int r = blockIdx.x, tid = threadIdx.x;
    if (tid < 16) {
        const u64 m = ld_u64(&spkO[r * 16 + tid]);
        bmp[tid] = m;
        pc[tid]  = __popcll(m);
    }
    __syncthreads();
    const int cnt = build_one<256>(bmp, pc, list, tid);
    __syncthreads();
    const float acc = gather1<256>(Wt_out, list, cnt, tid);
    out[r * 256 + tid] = acc + b_out[tid];
}

// ---------------------------------------------------------------------------
extern "C" void kernel_launch(void* const* d_in, const int* in_sizes, int n_in,
                              void* d_out, int out_size, void* d_ws, size_t ws_size,
                              hipStream_t stream) {
    (void)in_sizes; (void)n_in; (void)out_size; (void)ws_size;
    const float* inp    = (const float*)d_in[0];
    const float* W_pre  = (const float*)d_in[1];
    const float* b_pre  = (const float*)d_in[2];
    const float* W_ad   = (const float*)d_in[3];
    const float* b_ad   = (const float*)d_in[4];
    const float* W_post = (const float*)d_in[5];
    const float* b_post = (const float*)d_in[6];
    const float* W_out  = (const float*)d_in[7];
    const float* b_out  = (const float*)d_in[8];

    char* base = (char*)d_ws;
    int*  xcd_ctr  = (int*)base;                    // 8 counters, 128B apart
    int*  root_ctr = (int*)(base + 1024);
    int*  epoch    = (int*)(base + 1088);
    u64*  spkP     = (u64*)(base + 4096);           // 16 KB
    u64*  spkS     = (u64*)(base + 4096 + 16384);   // 16 KB
    u64*  spkO     = (u64*)(base + 4096 + 32768);   // 512 KB
    float* ws      = (float*)(base + 1048576);
    float* Wt_pre  = ws;
    float* Wt_post = Wt_pre  + 1536 * 1024;
    float* Wt_ad   = Wt_post + 1536 * 1024;
    float* Wt_out  = Wt_ad   + 1024 * 1024;
    float* IP_pre  = Wt_out  + 1024 * 256;
    float* IP_post = IP_pre  + 4096 * 1024;

    hipMemsetAsync(base, 0, 4096, stream);  // zero barrier counters + epoch

    transpose_k<<<dim3(48, 32), dim3(32, 8), 0, stream>>>(W_pre,  Wt_pre,  1024, 1536);
    transpose_k<<<dim3(48, 32), dim3(32, 8), 0, stream>>>(W_post, Wt_post, 1024, 1536);
    transpose_k<<<dim3(32, 32), dim3(32, 8), 0, stream>>>(W_ad,   Wt_ad,   1024, 1024);
    transpose_k<<<dim3(32, 8),  dim3(32, 8), 0, stream>>>(W_out,  Wt_out,  256,  1024);

    ip_gemm<<<dim3(4, 256), 256, 0, stream>>>(inp, Wt_pre,  b_pre,  IP_pre);
    ip_gemm<<<dim3(4, 256), 256, 0, stream>>>(inp, Wt_post, b_post, IP_post);

    rsnn_shared<<<256, 512, 0, stream>>>(Wt_pre, Wt_ad, Wt_post,
                                         IP_pre, IP_post, b_ad,
                                         spkP, spkS, spkO,
                                         xcd_ctr, root_ctr, epoch,
                                         (float*)d_out);

    out_gemm<<<4096, 256, 0, stream>>>(Wt_out, b_out, spkO, (float*)d_out);
}

// Round 4
// 1462.406 us; speedup vs baseline: 2.6545x; 1.3139x over previous
//
#include <hip/hip_runtime.h>

#pragma clang fp contract(off)

typedef unsigned long long u64;

#define ALPHA  0.9f
#define RHO    0.985f
#define BETA_A 1.8f
#define TH     1.0f

// ---------------------------------------------------------------------------
// Generic 32x32 tiled transpose: src[R][C] -> dst[C][R]
// ---------------------------------------------------------------------------
__global__ __launch_bounds__(256) void transpose_k(const float* __restrict__ src,
                                                   float* __restrict__ dst,
                                                   int R, int C) {
    __shared__ float tile[32][33];
    const int c0 = blockIdx.x * 32;
    const int r0 = blockIdx.y * 32;
    const int tx = threadIdx.x, ty = threadIdx.y;
#pragma unroll
    for (int i = 0; i < 4; ++i)
        tile[ty + i * 8][tx] = src[(r0 + ty + i * 8) * C + c0 + tx];
    __syncthreads();
#pragma unroll
    for (int i = 0; i < 4; ++i)
        dst[(c0 + ty + i * 8) * R + r0 + tx] = tile[tx][ty + i * 8];
}

// ---------------------------------------------------------------------------
// Input projection: out[r][n] = sum_k inp[r][k] * Wt[k][n] + bias[n]
// ---------------------------------------------------------------------------
__global__ __launch_bounds__(256) void ip_gemm(const float* __restrict__ inp,
                                               const float* __restrict__ Wt,
                                               const float* __restrict__ bias,
                                               float* __restrict__ out) {
    __shared__ __align__(16) float s_in[512 * 20];
    const int tid   = threadIdx.x;
    const int chunk = blockIdx.x;
    const int rbase = blockIdx.y * 16;

    for (int idx = tid; idx < 16 * 512; idx += 256) {
        const int r = idx >> 9, k = idx & 511;
        s_in[k * 20 + r] = inp[(rbase + r) * 512 + k];
    }
    __syncthreads();

    const int n = chunk * 256 + tid;
    float acc[16];
#pragma unroll
    for (int r = 0; r < 16; ++r) acc[r] = 0.f;

    for (int k = 0; k < 512; ++k) {
        const float w = Wt[k * 1024 + n];
        const float4* p = (const float4*)(s_in + k * 20);
        const float4 x0 = p[0], x1 = p[1], x2 = p[2], x3 = p[3];
        acc[0]  = fmaf(x0.x, w, acc[0]);  acc[1]  = fmaf(x0.y, w, acc[1]);
        acc[2]  = fmaf(x0.z, w, acc[2]);  acc[3]  = fmaf(x0.w, w, acc[3]);
        acc[4]  = fmaf(x1.x, w, acc[4]);  acc[5]  = fmaf(x1.y, w, acc[5]);
        acc[6]  = fmaf(x1.z, w, acc[6]);  acc[7]  = fmaf(x1.w, w, acc[7]);
        acc[8]  = fmaf(x2.x, w, acc[8]);  acc[9]  = fmaf(x2.y, w, acc[9]);
        acc[10] = fmaf(x2.z, w, acc[10]); acc[11] = fmaf(x2.w, w, acc[11]);
        acc[12] = fmaf(x3.x, w, acc[12]); acc[13] = fmaf(x3.y, w, acc[13]);
        acc[14] = fmaf(x3.z, w, acc[14]); acc[15] = fmaf(x3.w, w, acc[15]);
    }
    const float bn = bias[n];
#pragma unroll
    for (int r = 0; r < 16; ++r) out[(rbase + r) * 1024 + n] = acc[r] + bn;
}

// ---------------------------------------------------------------------------
// Agent-scope relaxed helpers (same intrinsics validated in round 3).
// ---------------------------------------------------------------------------
__device__ __forceinline__ u64 ld_u64(const u64* p) {
    return __hip_atomic_load(p, __ATOMIC_RELAXED, __HIP_MEMORY_SCOPE_AGENT);
}
__device__ __forceinline__ void st_u64(u64* p, u64 v) {
    __hip_atomic_store(p, v, __ATOMIC_RELAXED, __HIP_MEMORY_SCOPE_AGENT);
}
__device__ __forceinline__ int ld_i32(const int* p) {
    return __hip_atomic_load(p, __ATOMIC_RELAXED, __HIP_MEMORY_SCOPE_AGENT);
}
__device__ __forceinline__ void st_i32(int* p, int v) {
    __hip_atomic_store(p, v, __ATOMIC_RELAXED, __HIP_MEMORY_SCOPE_AGENT);
}

// Poll the 4 per-slice epoch slots of this pair's line until all >= e.
__device__ __forceinline__ void poll4(const int* slots, int e, int tid) {
    if (tid < 4) {
        int g = 0;
        while (ld_i32(&slots[tid]) < e && ++g < (1 << 24)) {}
    }
    __syncthreads();
}

// Build ordered index list from a 1024-bit map (own slice pre-zeroed).
template <int T>
__device__ __forceinline__ int build_one(const u64* bmp16, const int* pc16,
                                         int* list, int tid) {
    int total = 0;
#pragma unroll
    for (int w = 0; w < 16; ++w) total += pc16[w];
    for (int j = tid; j < 1024; j += T) {
        const int w = j >> 6, bit = j & 63;
        const u64 m = bmp16[w];
        if ((m >> bit) & 1ull) {
            int base = __popcll(m & ((1ull << bit) - 1ull));
            for (int q = 0; q < w; ++q) base += pc16[q];
            list[base] = j;
        }
    }
    return total;
}

template <int S>
__device__ __forceinline__ float gather1(const float* __restrict__ W,
                                         const int* __restrict__ list, int cnt, int col) {
    float a0 = 0.f, a1 = 0.f, a2 = 0.f, a3 = 0.f;
    int i = 0;
    for (; i + 4 <= cnt; i += 4) {
        const int4 j = *(const int4*)(list + i);
        a0 += W[j.x * S + col];
        a1 += W[j.y * S + col];
        a2 += W[j.z * S + col];
        a3 += W[j.w * S + col];
    }
    for (; i < cnt; ++i) a0 += W[list[i] * S + col];
    return (a0 + a1) + (a2 + a3);
}

__device__ __forceinline__ void gather2(const float* __restrict__ Wc,
                                        const float* __restrict__ Wa,
                                        const int* __restrict__ list, int cnt, int col,
                                        float& accC, float& accA) {
    float c0 = 0.f, c1 = 0.f, a0 = 0.f, a1 = 0.f;
    int i = 0;
    for (; i + 2 <= cnt; i += 2) {
        const int2 j = *(const int2*)(list + i);
        c0 += Wc[j.x * 1024 + col];
        a0 += Wa[j.x * 1024 + col];
        c1 += Wc[j.y * 1024 + col];
        a1 += Wa[j.y * 1024 + col];
    }
    if (i < cnt) {
        const int j = list[i];
        c0 += Wc[j * 1024 + col];
        a0 += Wa[j * 1024 + col];
    }
    accC = c0 + c1;
    accA = a0 + a1;
}

// ---------------------------------------------------------------------------
// Point-to-point main kernel: 256 blocks x 512 threads.
// bid = g*8+x; slice s=x>>1 (cols [s*256, s*256+256)); pair p=g*2+(x&1)
// (batches 2p, 2p+1). A batch-pair's 4 partner blocks (slices 0..3, on 4
// different XCDs) exchange 512-bit spike halves via parity-double-buffered
// bitmap lines + per-pair epoch lines. No global barrier. Exchange latency
// is hidden by gathering the block's OWN slice rows before polling partners.
// ---------------------------------------------------------------------------
__global__ __launch_bounds__(512) void rsnn_p2p(
    const float* __restrict__ Wt_pre,   // [1536][1024]
    const float* __restrict__ Wt_ad,    // [1024][1024]
    const float* __restrict__ Wt_post,  // [1536][1024]
    const float* __restrict__ IP_pre,   // [4096][1024]
    const float* __restrict__ IP_post,  // [4096][1024]
    const float* __restrict__ b_ad_p,   // [1024]
    u64* __restrict__ bitsP,            // [64][2][4][8]
    u64* __restrict__ bitsS,            // [64][2][4][8]
    u64* __restrict__ spkO,             // [4096][16]
    int* __restrict__ eps,              // [64][16]  (P: slots 0-3, S: 4-7)
    float* __restrict__ out)
{
    const int tid  = threadIdx.x;
    const int bid  = blockIdx.x;
    const int x    = bid & 7;
    const int g    = bid >> 3;
    const int s    = x >> 1;
    const int p    = g * 2 + (x & 1);
    const int bi   = tid >> 8;            // batch within pair
    const int c    = tid & 255;           // col within slice
    const int col  = s * 256 + c;
    const int b    = 2 * p + bi;
    const int wid  = tid >> 6;            // 0..7: bi = wid>>2, quarter = wid&3
    const int lane = tid & 63;
    const int wb   = wid >> 2;
    const int wq   = wid & 3;

    __shared__ u64 own[8];
    __shared__ int pcOwn[8];
    __shared__ u64 bmp[2][16];
    __shared__ int pc[2][16];
    __shared__ __align__(16) int listOwn[2][256];
    __shared__ __align__(16) int list[2][1024];

    int* epLine = eps + p * 16;

    float v_pre = 0.f, v_a = 0.f, ba = 0.f, v_post = 0.f, accA = 0.f;
    bool  sa = false;
    const float bad = b_ad_p[col];
    const float* WpreA  = Wt_pre  + 512 * 1024;
    const float* WpostA = Wt_post + 512 * 1024;

    for (int t = 0; t < 32; ++t) {
        const int row = t * 128 + b;
        const float ipre  = IP_pre [row * 1024 + col];
        const float ipost = IP_post[row * 1024 + col];
        for (int k = 0; k < 3; ++k) {
            const int e   = t * 3 + k + 1;
            const int par = e & 1;
            u64* myP = bitsP + ((p * 2 + par) * 4 + s) * 8;
            u64* myS = bitsS + ((p * 2 + par) * 4 + s) * 8;

            // ================= A: v_pre update, publish s_pre ==============
            v_pre = ALPHA * v_pre + ipre + accA;
            float d = v_pre - TH;
            const bool sp = d > 0.f;
            if (sp) v_pre = d;
            {
                const u64 m = __ballot(sp);
                if (lane == 0) { st_u64(&myP[wid], m); own[wid] = m; }
            }
            __syncthreads();                       // drain bit stores + LDS
            if (tid == 0) st_i32(&epLine[s], e);   // fire-and-forget
            if (tid < 8) pcOwn[tid] = __popcll(own[tid]);
            __syncthreads();

            // ---- own-slice B gather (hides partner latency) ----
            int cntOwn = pcOwn[bi * 4] + pcOwn[bi * 4 + 1] +
                         pcOwn[bi * 4 + 2] + pcOwn[bi * 4 + 3];
            {
                const u64 mw = own[bi * 4 + (c >> 6)];
                if ((mw >> (c & 63)) & 1ull) {
                    int base = __popcll(mw & ((1ull << (c & 63)) - 1ull));
                    for (int w = 0; w < (c >> 6); ++w) base += pcOwn[bi * 4 + w];
                    listOwn[bi][base] = s * 256 + c;
                }
            }
            __syncthreads();
            float accB = gather1<1024>(Wt_ad, listOwn[bi], cntOwn, col);

            // ---- partner halves ----
            poll4(epLine, e, tid);
            if (tid < 32) {
                const int sl = tid >> 3, w8 = tid & 7;
                u64 mm = 0;
                if (sl != s)
                    mm = ld_u64(&bitsP[((p * 2 + par) * 4 + sl) * 8 + w8]);
                bmp[w8 >> 2][sl * 4 + (w8 & 3)] = mm;
                pc [w8 >> 2][sl * 4 + (w8 & 3)] = __popcll(mm);
            }
            __syncthreads();
            const int cP0 = build_one<512>(bmp[0], pc[0], list[0], tid);
            const int cP1 = build_one<512>(bmp[1], pc[1], list[1], tid);
            __syncthreads();
            accB += gather1<1024>(Wt_ad, list[bi], bi ? cP1 : cP0, col);

            // ================= B: v_a update, publish s_a ==================
            v_a = ALPHA * v_a + accB + bad;
            const float th = TH + BETA_A * ba;
            d = v_a - th;
            sa = d > 0.f;
            if (sa) v_a = d;
            ba = RHO * ba + (sa ? 1.f : 0.f);
            {
                const u64 m = __ballot(sa);
                if (lane == 0) { st_u64(&myS[wid], m); own[wid] = m; }
            }
            __syncthreads();
            if (tid == 0) st_i32(&epLine[4 + s], e);
            if (tid < 8) pcOwn[tid] = __popcll(own[tid]);
            __syncthreads();

            // ---- own-slice C + next-A gather ----
            int cntOwnS = pcOwn[bi * 4] + pcOwn[bi * 4 + 1] +
                          pcOwn[bi * 4 + 2] + pcOwn[bi * 4 + 3];
            {
                const u64 mw = own[bi * 4 + (c >> 6)];
                if ((mw >> (c & 63)) & 1ull) {
                    int base = __popcll(mw & ((1ull << (c & 63)) - 1ull));
                    for (int w = 0; w < (c >> 6); ++w) base += pcOwn[bi * 4 + w];
                    listOwn[bi][base] = s * 256 + c;
                }
            }
            __syncthreads();
            float accC, accAo;
            gather2(WpostA, WpreA, listOwn[bi], cntOwnS, col, accC, accAo);

            // ---- partner halves ----
            poll4(epLine + 4, e, tid);
            if (tid < 32) {
                const int sl = tid >> 3, w8 = tid & 7;
                u64 mm = 0;
                if (sl != s)
                    mm = ld_u64(&bitsS[((p * 2 + par) * 4 + sl) * 8 + w8]);
                bmp[w8 >> 2][sl * 4 + (w8 & 3)] = mm;
                pc [w8 >> 2][sl * 4 + (w8 & 3)] = __popcll(mm);
            }
            __syncthreads();
            const int cS0 = build_one<512>(bmp[0], pc[0], list[0], tid);
            const int cS1 = build_one<512>(bmp[1], pc[1], list[1], tid);
            __syncthreads();
            float accCp, accAp;
            gather2(WpostA, WpreA, list[bi], bi ? cS1 : cS0, col, accCp, accAp);
            accC += accCp;
            accA = accAo + accAp;

            // ================= C: v_post update ===========================
            v_post = ALPHA * v_post + ipost + accC;
            d = v_post - TH;
            const bool spost = d > 0.f;
            if (spost) v_post = d;

            if (k == 2) {
                const u64 m = __ballot(spost);
                if (lane == 0)
                    st_u64(&spkO[(t * 128 + 2 * p + wb) * 16 + s * 4 + wq], m);
                if (t == 31)
                    out[32 * 128 * 256 + b * 1024 + col] = sa ? 1.f : 0.f;
            }
        }
    }
}

// ---------------------------------------------------------------------------
// Final output GEMM: o[r] = s_post[r] @ W_out.T + b_out, from spkO bitmaps.
// ---------------------------------------------------------------------------
__global__ __launch_bounds__(256) void out_gemm(const float* __restrict__ Wt_out,
                                                const float* __restrict__ b_out,
                                                const u64* __restrict__ spkO,
                                                float* __restrict__ out) {
    __shared__ u64 bmp[16];
    __shared__ int pc[16];
    __shared__ __align__(16) int list[1024];
    const int r = blockIdx.x, tid = threadIdx.x;
    if (tid < 16) {
        const u64 m = ld_u64(&spkO[r * 16 + tid]);
        bmp[tid] = m;
        pc[tid]  = __popcll(m);
    }
    __syncthreads();
    const int cnt = build_one<256>(bmp, pc, list, tid);
    __syncthreads();
    const float acc = gather1<256>(Wt_out, list, cnt, tid);
    out[r * 256 + tid] = acc + b_out[tid];
}

// ---------------------------------------------------------------------------
extern "C" void kernel_launch(void* const* d_in, const int* in_sizes, int n_in,
                              void* d_out, int out_size, void* d_ws, size_t ws_size,
                              hipStream_t stream) {
    (void)in_sizes; (void)n_in; (void)out_size; (void)ws_size;
    const float* inp    = (const float*)d_in[0];
    const float* W_pre  = (const float*)d_in[1];
    const float* b_pre  = (const float*)d_in[2];
    const float* W_ad   = (const float*)d_in[3];
    const float* b_ad   = (const float*)d_in[4];
    const float* W_post = (const float*)d_in[5];
    const float* b_post = (const float*)d_in[6];
    const float* W_out  = (const float*)d_in[7];
    const float* b_out  = (const float*)d_in[8];

    char* base = (char*)d_ws;
    int*  eps   = (int*)base;                        // 64 pairs x 16 ints = 4KB
    u64*  bitsP = (u64*)(base + 4096);               // 32KB
    u64*  bitsS = (u64*)(base + 4096 + 32768);       // 32KB
    u64*  spkO  = (u64*)(base + 131072);             // 512KB
    float* ws      = (float*)(base + 1048576);
    float* Wt_pre  = ws;
    float* Wt_post = Wt_pre  + 1536 * 1024;
    float* Wt_ad   = Wt_post + 1536 * 1024;
    float* Wt_out  = Wt_ad   + 1024 * 1024;
    float* IP_pre  = Wt_out  + 1024 * 256;
    float* IP_post = IP_pre  + 4096 * 1024;

    hipMemsetAsync(base, 0, 4096, stream);  // zero epoch lines each launch

    transpose_k<<<dim3(48, 32), dim3(32, 8), 0, stream>>>(W_pre,  Wt_pre,  1024, 1536);
    transpose_k<<<dim3(48, 32), dim3(32, 8), 0, stream>>>(W_post, Wt_post, 1024, 1536);
    transpose_k<<<dim3(32, 32), dim3(32, 8), 0, stream>>>(W_ad,   Wt_ad,   1024, 1024);
    transpose_k<<<dim3(32, 8),  dim3(32, 8), 0, stream>>>(W_out,  Wt_out,  256,  1024);

    ip_gemm<<<dim3(4, 256), 256, 0, stream>>>(inp, Wt_pre,  b_pre,  IP_pre);
    ip_gemm<<<dim3(4, 256), 256, 0, stream>>>(inp, Wt_post, b_post, IP_post);

    rsnn_p2p<<<256, 512, 0, stream>>>(Wt_pre, Wt_ad, Wt_post,
                                      IP_pre, IP_post, b_ad,
                                      bitsP, bitsS, spkO, eps,
                                      (float*)d_out);

    out_gemm<<<4096, 256, 0, stream>>>(Wt_out, b_out, spkO, (float*)d_out);
}

// Round 5
// 1394.253 us; speedup vs baseline: 2.7843x; 1.0489x over previous
//
#include <hip/hip_runtime.h>

#pragma clang fp contract(off)

typedef unsigned long long u64;

#define ALPHA  0.9f
#define RHO    0.985f
#define BETA_A 1.8f
#define TH     1.0f
#define CAP    (1 << 22)

// ---------------------------------------------------------------------------
// Generic 32x32 tiled transpose: src[R][C] -> dst[C][R]
// ---------------------------------------------------------------------------
__global__ __launch_bounds__(256) void transpose_k(const float* __restrict__ src,
                                                   float* __restrict__ dst,
                                                   int R, int C) {
    __shared__ float tile[32][33];
    const int c0 = blockIdx.x * 32;
    const int r0 = blockIdx.y * 32;
    const int tx = threadIdx.x, ty = threadIdx.y;
#pragma unroll
    for (int i = 0; i < 4; ++i)
        tile[ty + i * 8][tx] = src[(r0 + ty + i * 8) * C + c0 + tx];
    __syncthreads();
#pragma unroll
    for (int i = 0; i < 4; ++i)
        dst[(c0 + ty + i * 8) * R + r0 + tx] = tile[tx][ty + i * 8];
}

// ---------------------------------------------------------------------------
// Input projection: out[r][n] = sum_k inp[r][k] * Wt[k][n] + bias[n]
// ---------------------------------------------------------------------------
__global__ __launch_bounds__(256) void ip_gemm(const float* __restrict__ inp,
                                               const float* __restrict__ Wt,
                                               const float* __restrict__ bias,
                                               float* __restrict__ out) {
    __shared__ __align__(16) float s_in[512 * 20];
    const int tid   = threadIdx.x;
    const int chunk = blockIdx.x;
    const int rbase = blockIdx.y * 16;

    for (int idx = tid; idx < 16 * 512; idx += 256) {
        const int r = idx >> 9, k = idx & 511;
        s_in[k * 20 + r] = inp[(rbase + r) * 512 + k];
    }
    __syncthreads();

    const int n = chunk * 256 + tid;
    float acc[16];
#pragma unroll
    for (int r = 0; r < 16; ++r) acc[r] = 0.f;

    for (int k = 0; k < 512; ++k) {
        const float w = Wt[k * 1024 + n];
        const float4* p = (const float4*)(s_in + k * 20);
        const float4 x0 = p[0], x1 = p[1], x2 = p[2], x3 = p[3];
        acc[0]  = fmaf(x0.x, w, acc[0]);  acc[1]  = fmaf(x0.y, w, acc[1]);
        acc[2]  = fmaf(x0.z, w, acc[2]);  acc[3]  = fmaf(x0.w, w, acc[3]);
        acc[4]  = fmaf(x1.x, w, acc[4]);  acc[5]  = fmaf(x1.y, w, acc[5]);
        acc[6]  = fmaf(x1.z, w, acc[6]);  acc[7]  = fmaf(x1.w, w, acc[7]);
        acc[8]  = fmaf(x2.x, w, acc[8]);  acc[9]  = fmaf(x2.y, w, acc[9]);
        acc[10] = fmaf(x2.z, w, acc[10]); acc[11] = fmaf(x2.w, w, acc[11]);
        acc[12] = fmaf(x3.x, w, acc[12]); acc[13] = fmaf(x3.y, w, acc[13]);
        acc[14] = fmaf(x3.z, w, acc[14]); acc[15] = fmaf(x3.w, w, acc[15]);
    }
    const float bn = bias[n];
#pragma unroll
    for (int r = 0; r < 16; ++r) out[(rbase + r) * 1024 + n] = acc[r] + bn;
}

// ---------------------------------------------------------------------------
__device__ __forceinline__ u64 ld_u64(const u64* p) {
    return __hip_atomic_load(p, __ATOMIC_RELAXED, __HIP_MEMORY_SCOPE_AGENT);
}
__device__ __forceinline__ void st_u64(u64* p, u64 v) {
    __hip_atomic_store(p, v, __ATOMIC_RELAXED, __HIP_MEMORY_SCOPE_AGENT);
}

// 4-accumulator ordered gather over a list segment (16B-aligned base).
template <int S>
__device__ __forceinline__ float gather1(const float* __restrict__ W,
                                         const int* __restrict__ list, int cnt, int col) {
    float a0 = 0.f, a1 = 0.f, a2 = 0.f, a3 = 0.f;
    int i = 0;
    for (; i + 4 <= cnt; i += 4) {
        const int4 j = *(const int4*)(list + i);
        a0 += W[j.x * S + col];
        a1 += W[j.y * S + col];
        a2 += W[j.z * S + col];
        a3 += W[j.w * S + col];
    }
    for (; i < cnt; ++i) a0 += W[list[i] * S + col];
    return (a0 + a1) + (a2 + a3);
}

// Build split list: own-slice rows (asc) at [0,cntOwn), partner rows (asc)
// at [ownPad, ownPad + total-cntOwn), ownPad = 4-aligned. Stride-256 per batch.
__device__ __forceinline__ int build_split(const u64* bmp16, const int* pc16, int s,
                                           int* list, int c0, int* cntOwn_out) {
    int cntOwn = pc16[s * 4] + pc16[s * 4 + 1] + pc16[s * 4 + 2] + pc16[s * 4 + 3];
    const int ownPad = (cntOwn + 3) & ~3;
    int total = 0;
#pragma unroll
    for (int w = 0; w < 16; ++w) total += pc16[w];
    for (int j = c0; j < 1024; j += 256) {
        const int w = j >> 6, bit = j & 63;
        const u64 m = bmp16[w];
        if ((m >> bit) & 1ull) {
            int base = __popcll(m & ((1ull << bit) - 1ull));
            if ((w >> 2) == s) {
                for (int q = s * 4; q < w; ++q) base += pc16[q];
            } else {
                base += ownPad;
#pragma unroll
                for (int w2 = 0; w2 < 16; ++w2)
                    if (w2 < w && (w2 >> 2) != s) base += pc16[w2];
            }
            list[base] = j;
        }
    }
    *cntOwn_out = cntOwn;
    return total;
}

// ---------------------------------------------------------------------------
// Main kernel: 256 blocks x 512 threads; slice s = (bid&7)>>1 (256 cols on
// one XCD -> L2-resident weight slices); pair p = (bid>>3)*2 + (bid&1).
// Exchange lines: 8 u64 of (epoch<<32 | 32 spike bits) -- self-validating,
// single-LLC-trip publish and poll. v_post runs one phase behind (its gather
// fills exchange-1's window); own-slice partial gathers fill exchange-2's.
// ---------------------------------------------------------------------------
__global__ __launch_bounds__(512) void rsnn_wave(
    const float* __restrict__ Wt_pre,   // [1536][1024]
    const float* __restrict__ Wt_ad,    // [1024][1024]
    const float* __restrict__ Wt_post,  // [1536][1024]
    const float* __restrict__ IP_pre,   // [4096][1024]
    const float* __restrict__ IP_post,  // [4096][1024]
    const float* __restrict__ b_ad_p,   // [1024]
    u64* __restrict__ lines,            // [64][2][2][4][2][8]
    u64* __restrict__ spkO,             // [4096][16]
    float* __restrict__ out)
{
    const int tid  = threadIdx.x;
    const int bid  = blockIdx.x;
    const int x    = bid & 7;
    const int g    = bid >> 3;
    const int s    = x >> 1;
    const int p    = g * 2 + (x & 1);
    const int bi   = tid >> 8;
    const int c    = tid & 255;
    const int col  = s * 256 + c;
    const int b    = 2 * p + bi;
    const int wid  = tid >> 6;
    const int lane = tid & 63;

    __shared__ u64 ownP[8], ownS[8];
    __shared__ u64 bmp[2][16];
    __shared__ int pc[2][16];
    __shared__ __align__(16) int listP[2][1024];
    __shared__ __align__(16) int listS[2][1024];

    float v_pre = 0.f, v_a = 0.f, ba = 0.f, v_post = 0.f;
    float accA_carry = 0.f, accC_carry = 0.f;
    int   cntS_prev = 0, ownS_prev = 0, padS_prev = 0;
    bool  sa = false;
    const float bad = b_ad_p[col];
    const float* WpreA  = Wt_pre  + 512 * 1024;
    const float* WpostA = Wt_post + 512 * 1024;
    float ipre = 0.f, ipost = 0.f, ipost_prev = 0.f;
    const u64 M32 = 0xffffffffull;

    for (int e = 1; e <= 96; ++e) {
        const int t = (e - 1) / 3, k = (e - 1) % 3;
        if (k == 0) {
            const int row = t * 128 + b;
            ipost_prev = ipost;
            ipre  = IP_pre [row * 1024 + col];
            ipost = IP_post[row * 1024 + col];
        }
        const int par = e & 1;
        u64* baseLn = lines + ((p * 2 + par) * 2) * 4 * 2 * 8;  // [ty][sl][bb][8]

        // ================= A: v_pre update, publish s_pre ==================
        v_pre = ALPHA * v_pre + ipre + accA_carry;
        float d = v_pre - TH;
        const bool sp = d > 0.f;
        if (sp) v_pre = d;
        { const u64 m = __ballot(sp); if (lane == 0) ownP[wid] = m; }
        __syncthreads();                                        // S1
        if (tid < 2) {
            u64* ln = baseLn + (s * 2 + tid) * 8;               // ty=0
            const u64 eh = ((u64)e) << 32;
#pragma unroll
            for (int q = 0; q < 4; ++q) {
                const u64 bb = ownP[tid * 4 + q];
                st_u64(ln + 2 * q,     eh | (bb & M32));
                st_u64(ln + 2 * q + 1, eh | (bb >> 32));
            }
        }

        // ---- FILL-1: finish v_post(e-1) while exchange-1 propagates ----
        if (e >= 2) {
            const float accC = accC_carry +
                gather1<1024>(WpostA, listS[bi] + padS_prev,
                              cntS_prev - ownS_prev, col);
            const float ip_use = (k == 0) ? ipost_prev : ipost;
            v_post = ALPHA * v_post + ip_use + accC;
            float dd = v_post - TH;
            const bool spost = dd > 0.f;
            if (spost) v_post = dd;
            if (e >= 4 && e % 3 == 1) {
                const u64 m = __ballot(spost);
                if (lane == 0)
                    st_u64(&spkO[(((e - 2) / 3) * 128 + 2 * p + (wid >> 2)) * 16 +
                                 s * 4 + (wid & 3)], m);
            }
        }

        // ---- poll exchange-1 (wave 1) + own bits -> bmp ----
        if (tid >= 64 && tid < 70) {
            const int idx = tid - 64, rbi = idx & 1, ridx = idx >> 1;
            const int rsl = ridx + (ridx >= s ? 1 : 0);
            const u64* ln = baseLn + (rsl * 2 + rbi) * 8;
            u64 w[8];
            int gd = 0; bool ok = false;
            while (!ok && ++gd < CAP) {
                ok = true;
#pragma unroll
                for (int i = 0; i < 8; ++i) {
                    w[i] = ld_u64(ln + i);
                    ok &= ((w[i] >> 32) == (u64)e);
                }
            }
#pragma unroll
            for (int q = 0; q < 4; ++q) {
                const u64 m = (w[2 * q] & M32) | ((w[2 * q + 1] & M32) << 32);
                bmp[rbi][rsl * 4 + q] = m;
                pc [rbi][rsl * 4 + q] = __popcll(m);
            }
        }
        if (tid < 8) {
            const u64 m = ownP[tid];
            bmp[tid >> 2][s * 4 + (tid & 3)] = m;
            pc [tid >> 2][s * 4 + (tid & 3)] = __popcll(m);
        }
        __syncthreads();                                        // S2
        int cntOwnP;
        const int cntP = build_split(bmp[bi], pc[bi], s, listP[bi], c, &cntOwnP);
        const int padP = (cntOwnP + 3) & ~3;
        __syncthreads();                                        // S3

        // ================= B: v_a update, publish s_a ======================
        float accB = gather1<1024>(Wt_ad, listP[bi], cntOwnP, col);
        accB += gather1<1024>(Wt_ad, listP[bi] + padP, cntP - cntOwnP, col);
        v_a = ALPHA * v_a + accB + bad;
        const float th = TH + BETA_A * ba;
        d = v_a - th;
        sa = d > 0.f;
        if (sa) v_a = d;
        ba = RHO * ba + (sa ? 1.f : 0.f);
        { const u64 m = __ballot(sa); if (lane == 0) ownS[wid] = m; }
        __syncthreads();                                        // S4
        if (tid < 2) {
            u64* ln = baseLn + (8 + s * 2 + tid) * 8;           // ty=1
            const u64 eh = ((u64)e) << 32;
#pragma unroll
            for (int q = 0; q < 4; ++q) {
                const u64 bb = ownS[tid * 4 + q];
                st_u64(ln + 2 * q,     eh | (bb & M32));
                st_u64(ln + 2 * q + 1, eh | (bb >> 32));
            }
        }

        // ---- FILL-2: own-slice partial A/C gathers (bit-scan, asc order) ----
        float aown = 0.f, cown = 0.f;
#pragma unroll
        for (int q = 0; q < 4; ++q) {
            u64 m = ownS[bi * 4 + q];
            while (m) {
                const int bt = __builtin_ctzll(m);
                m &= m - 1;
                const int j = s * 256 + q * 64 + bt;
                aown += WpreA [j * 1024 + col];
                cown += WpostA[j * 1024 + col];
            }
        }
        if (e == 96)
            out[32 * 128 * 256 + b * 1024 + col] = sa ? 1.f : 0.f;

        // ---- poll exchange-2 (wave 1) + own bits -> bmp ----
        if (tid >= 64 && tid < 70) {
            const int idx = tid - 64, rbi = idx & 1, ridx = idx >> 1;
            const int rsl = ridx + (ridx >= s ? 1 : 0);
            const u64* ln = baseLn + (8 + rsl * 2 + rbi) * 8;
            u64 w[8];
            int gd = 0; bool ok = false;
            while (!ok && ++gd < CAP) {
                ok = true;
#pragma unroll
                for (int i = 0; i < 8; ++i) {
                    w[i] = ld_u64(ln + i);
                    ok &= ((w[i] >> 32) == (u64)e);
                }
            }
#pragma unroll
            for (int q = 0; q < 4; ++q) {
                const u64 m = (w[2 * q] & M32) | ((w[2 * q + 1] & M32) << 32);
                bmp[rbi][rsl * 4 + q] = m;
                pc [rbi][rsl * 4 + q] = __popcll(m);
            }
        }
        if (tid < 8) {
            const u64 m = ownS[tid];
            bmp[tid >> 2][s * 4 + (tid & 3)] = m;
            pc [tid >> 2][s * 4 + (tid & 3)] = __popcll(m);
        }
        __syncthreads();                                        // S5
        int cntOwnS;
        cntS_prev = build_split(bmp[bi], pc[bi], s, listS[bi], c, &cntOwnS);
        ownS_prev = cntOwnS;
        padS_prev = (cntOwnS + 3) & ~3;
        __syncthreads();                                        // S6

        // ---- complete next-phase A accumulator (partner part) ----
        accA_carry = aown + gather1<1024>(WpreA, listS[bi] + padS_prev,
                                          cntS_prev - ownS_prev, col);
        accC_carry = cown;
    }

    // ---- epilogue: v_post(96) ----
    {
        const float accC = accC_carry +
            gather1<1024>(WpostA, listS[bi] + padS_prev, cntS_prev - ownS_prev, col);
        v_post = ALPHA * v_post + ipost + accC;
        const float dd = v_post - TH;
        const bool spost = dd > 0.f;
        const u64 m = __ballot(spost);
        if (lane == 0)
            st_u64(&spkO[(31 * 128 + 2 * p + (wid >> 2)) * 16 + s * 4 + (wid & 3)], m);
    }
}

// ---------------------------------------------------------------------------
// Final output GEMM: o[r] = s_post[r] @ W_out.T + b_out, from spkO bitmaps.
// ---------------------------------------------------------------------------
__global__ __launch_bounds__(256) void out_gemm(const float* __restrict__ Wt_out,
                                                const float* __restrict__ b_out,
                                                const u64* __restrict__ spkO,
                                                float* __restrict__ out) {
    __shared__ u64 bmp[16];
    __shared__ int pc[16];
    __shared__ __align__(16) int list[1024];
    const int r = blockIdx.x, tid = threadIdx.x;
    if (tid < 16) {
        const u64 m = ld_u64(&spkO[r * 16 + tid]);
        bmp[tid] = m;
        pc[tid]  = __popcll(m);
    }
    __syncthreads();
    int total = 0;
#pragma unroll
    for (int w = 0; w < 16; ++w) total += pc[w];
    for (int j = tid; j < 1024; j += 256) {
        const int w = j >> 6, bit = j & 63;
        const u64 m = bmp[w];
        if ((m >> bit) & 1ull) {
            int base = __popcll(m & ((1ull << bit) - 1ull));
            for (int q = 0; q < w; ++q) base += pc[q];
            list[base] = j;
        }
    }
    __syncthreads();
    const float acc = gather1<256>(Wt_out, list, total, tid);
    out[r * 256 + tid] = acc + b_out[tid];
}

// ---------------------------------------------------------------------------
extern "C" void kernel_launch(void* const* d_in, const int* in_sizes, int n_in,
                              void* d_out, int out_size, void* d_ws, size_t ws_size,
                              hipStream_t stream) {
    (void)in_sizes; (void)n_in; (void)out_size; (void)ws_size;
    const float* inp    = (const float*)d_in[0];
    const float* W_pre  = (const float*)d_in[1];
    const float* b_pre  = (const float*)d_in[2];
    const float* W_ad   = (const float*)d_in[3];
    const float* b_ad   = (const float*)d_in[4];
    const float* W_post = (const float*)d_in[5];
    const float* b_post = (const float*)d_in[6];
    const float* W_out  = (const float*)d_in[7];
    const float* b_out  = (const float*)d_in[8];

    char* base = (char*)d_ws;
    u64*  lines = (u64*)(base + 4096);               // 128 KB exchange lines
    u64*  spkO  = (u64*)(base + 147456);             // 512 KB
    float* ws      = (float*)(base + 1048576);
    float* Wt_pre  = ws;
    float* Wt_post = Wt_pre  + 1536 * 1024;
    float* Wt_ad   = Wt_post + 1536 * 1024;
    float* Wt_out  = Wt_ad   + 1024 * 1024;
    float* IP_pre  = Wt_out  + 1024 * 256;
    float* IP_post = IP_pre  + 4096 * 1024;

    hipMemsetAsync(base, 0, 4096 + 131072, stream);  // zero exchange lines

    transpose_k<<<dim3(48, 32), dim3(32, 8), 0, stream>>>(W_pre,  Wt_pre,  1024, 1536);
    transpose_k<<<dim3(48, 32), dim3(32, 8), 0, stream>>>(W_post, Wt_post, 1024, 1536);
    transpose_k<<<dim3(32, 32), dim3(32, 8), 0, stream>>>(W_ad,   Wt_ad,   1024, 1024);
    transpose_k<<<dim3(32, 8),  dim3(32, 8), 0, stream>>>(W_out,  Wt_out,  256,  1024);

    ip_gemm<<<dim3(4, 256), 256, 0, stream>>>(inp, Wt_pre,  b_pre,  IP_pre);
    ip_gemm<<<dim3(4, 256), 256, 0, stream>>>(inp, Wt_post, b_post, IP_post);

    rsnn_wave<<<256, 512, 0, stream>>>(Wt_pre, Wt_ad, Wt_post,
                                       IP_pre, IP_post, b_ad,
                                       lines, spkO, (float*)d_out);

    out_gemm<<<4096, 256, 0, stream>>>(Wt_out, b_out, spkO, (float*)d_out);
}

// Round 7
// 1083.852 us; speedup vs baseline: 3.5817x; 1.2864x over previous
//
#include <hip/hip_runtime.h>

#pragma clang fp contract(off)

typedef unsigned long long u64;
typedef unsigned int u32;

#define ALPHA  0.9f
#define RHO    0.985f
#define BETA_A 1.8f
#define TH     1.0f
#define CAP    (1 << 24)

// ---------------------------------------------------------------------------
// Generic 32x32 tiled transpose: src[R][C] -> dst[C][R]
// ---------------------------------------------------------------------------
__global__ __launch_bounds__(256) void transpose_k(const float* __restrict__ src,
                                                   float* __restrict__ dst,
                                                   int R, int C) {
    __shared__ float tile[32][33];
    const int c0 = blockIdx.x * 32;
    const int r0 = blockIdx.y * 32;
    const int tx = threadIdx.x, ty = threadIdx.y;
#pragma unroll
    for (int i = 0; i < 4; ++i)
        tile[ty + i * 8][tx] = src[(r0 + ty + i * 8) * C + c0 + tx];
    __syncthreads();
#pragma unroll
    for (int i = 0; i < 4; ++i)
        dst[(c0 + ty + i * 8) * R + r0 + tx] = tile[tx][ty + i * 8];
}

// ---------------------------------------------------------------------------
// Input projection: out[r][n] = sum_k inp[r][k] * Wt[k][n] + bias[n]
// ---------------------------------------------------------------------------
__global__ __launch_bounds__(256) void ip_gemm(const float* __restrict__ inp,
                                               const float* __restrict__ Wt,
                                               const float* __restrict__ bias,
                                               float* __restrict__ out) {
    __shared__ __align__(16) float s_in[512 * 20];
    const int tid   = threadIdx.x;
    const int chunk = blockIdx.x;
    const int rbase = blockIdx.y * 16;

    for (int idx = tid; idx < 16 * 512; idx += 256) {
        const int r = idx >> 9, k = idx & 511;
        s_in[k * 20 + r] = inp[(rbase + r) * 512 + k];
    }
    __syncthreads();

    const int n = chunk * 256 + tid;
    float acc[16];
#pragma unroll
    for (int r = 0; r < 16; ++r) acc[r] = 0.f;

    for (int k = 0; k < 512; ++k) {
        const float w = Wt[k * 1024 + n];
        const float4* p = (const float4*)(s_in + k * 20);
        const float4 x0 = p[0], x1 = p[1], x2 = p[2], x3 = p[3];
        acc[0]  = fmaf(x0.x, w, acc[0]);  acc[1]  = fmaf(x0.y, w, acc[1]);
        acc[2]  = fmaf(x0.z, w, acc[2]);  acc[3]  = fmaf(x0.w, w, acc[3]);
        acc[4]  = fmaf(x1.x, w, acc[4]);  acc[5]  = fmaf(x1.y, w, acc[5]);
        acc[6]  = fmaf(x1.z, w, acc[6]);  acc[7]  = fmaf(x1.w, w, acc[7]);
        acc[8]  = fmaf(x2.x, w, acc[8]);  acc[9]  = fmaf(x2.y, w, acc[9]);
        acc[10] = fmaf(x2.z, w, acc[10]); acc[11] = fmaf(x2.w, w, acc[11]);
        acc[12] = fmaf(x3.x, w, acc[12]); acc[13] = fmaf(x3.y, w, acc[13]);
        acc[14] = fmaf(x3.z, w, acc[14]); acc[15] = fmaf(x3.w, w, acc[15]);
    }
    const float bn = bias[n];
#pragma unroll
    for (int r = 0; r < 16; ++r) out[(rbase + r) * 1024 + n] = acc[r] + bn;
}

// ---------------------------------------------------------------------------
__device__ __forceinline__ u64 ld_u64(const u64* p) {
    return __hip_atomic_load(p, __ATOMIC_RELAXED, __HIP_MEMORY_SCOPE_AGENT);
}
__device__ __forceinline__ void st_u64(u64* p, u64 v) {
    __hip_atomic_store(p, v, __ATOMIC_RELAXED, __HIP_MEMORY_SCOPE_AGENT);
}

// Gather over byte-offset list segment [i0, i1), i0 % 4 == 0.
// Entries are row byte-offsets (j*4096); address = uniform base + 32-bit off.
__device__ __forceinline__ float gatherseg(const char* __restrict__ Wb,
                                           const int* __restrict__ list,
                                           int i0, int i1, int colB) {
    float a0 = 0.f, a1 = 0.f, a2 = 0.f, a3 = 0.f;
    int i = i0;
    for (; i + 4 <= i1; i += 4) {
        const int4 j = *(const int4*)(list + i);
        a0 += *(const float*)(Wb + (u32)(j.x + colB));
        a1 += *(const float*)(Wb + (u32)(j.y + colB));
        a2 += *(const float*)(Wb + (u32)(j.z + colB));
        a3 += *(const float*)(Wb + (u32)(j.w + colB));
    }
    for (; i < i1; ++i) a0 += *(const float*)(Wb + (u32)(list[i] + colB));
    return (a0 + a1) + (a2 + a3);
}

// index-based gather for out_gemm
__device__ __forceinline__ float gather_idx(const float* __restrict__ W,
                                            const int* __restrict__ list, int cnt, int col) {
    float a0 = 0.f, a1 = 0.f, a2 = 0.f, a3 = 0.f;
    int i = 0;
    for (; i + 4 <= cnt; i += 4) {
        const int4 j = *(const int4*)(list + i);
        a0 += W[j.x * 256 + col];
        a1 += W[j.y * 256 + col];
        a2 += W[j.z * 256 + col];
        a3 += W[j.w * 256 + col];
    }
    for (; i < cnt; ++i) a0 += W[list[i] * 256 + col];
    return (a0 + a1) + (a2 + a3);
}

// ---------------------------------------------------------------------------
// Producer-consumer main kernel: 256 blocks x 640 threads.
// Waves 0-7 compute (slice s = (bid&7)>>1: cols [s*256,s*256+256), pair
// p = (bid>>3)*2+(bid&1): batches 2p,2p+1). Wave 8 polls exchange-1 (s_pre)
// and builds listP; wave 9 polls exchange-2 (s_a) and builds listS[par].
// Publish: each compute wave's lane0 stores 2 epoch-tagged words
// ((e<<32)|bits32) immediately after its ballot -- no barrier before publish.
// 2 barriers per phase (B1 releases listP, B2 releases listS).
// FILL-2 at epoch e finishes v_post of phase ph=e-1; s_post is emitted when
// k(ph)=(ph-1)%3==2  <=>  e%3==1  (round-6 bug: used (e-1)%3==2, wrong k).
// ---------------------------------------------------------------------------
__global__ __launch_bounds__(640) void rsnn_pc(
    const float* __restrict__ Wt_pre,   // [1536][1024]
    const float* __restrict__ Wt_ad,    // [1024][1024]
    const float* __restrict__ Wt_post,  // [1536][1024]
    const float* __restrict__ IP_pre,   // [4096][1024]
    const float* __restrict__ IP_post,  // [4096][1024]
    const float* __restrict__ b_ad_p,   // [1024]
    u64* __restrict__ lines,            // [64 pairs][2 par][2 ty][64]
    u64* __restrict__ spkO,             // [4096][16]
    float* __restrict__ out)
{
    const int tid  = threadIdx.x;
    const int bid  = blockIdx.x;
    const int x    = bid & 7;
    const int g    = bid >> 3;
    const int s    = x >> 1;
    const int p    = g * 2 + (x & 1);
    const int wid  = tid >> 6;
    const int lane = tid & 63;

    __shared__ __align__(16) int listP[2][1024];      // [bi]
    __shared__ __align__(16) int listS[2][2][1024];   // [par][bi]
    __shared__ int cntP_ls[2], cntS_ls[2][2];

    const char* WadB    = (const char*)Wt_ad;
    const char* WpreAB  = (const char*)(Wt_pre  + 512 * 1024);
    const char* WpostAB = (const char*)(Wt_post + 512 * 1024);

    if (wid < 8) {
        // ============================ compute ============================
        const int bi   = tid >> 8;
        const int c    = tid & 255;
        const int col  = s * 256 + c;
        const int b    = 2 * p + bi;
        const int q    = wid & 3;
        const int colB = col * 4;

        float v_pre = 0.f, v_a = 0.f, ba = 0.f, v_post = 0.f, accA = 0.f;
        bool  sa = false;
        const float bad = b_ad_p[col];
        float g1 = 0.f;
        int halfPrev = 0, cntPrev = 0, parPrev = 0;

        for (int e = 1; e <= 96; ++e) {
            const int par = e & 1;
            const int t   = (e - 1) / 3;
            const float ipre = IP_pre[(t * 128 + b) * 1024 + col];
            u64* ln0 = lines + ((p * 2 + par) * 2 + 0) * 64;
            u64* ln1 = lines + ((p * 2 + par) * 2 + 1) * 64;

            // ---- A: v_pre update, immediate per-wave publish ----
            v_pre = ALPHA * v_pre + ipre + accA;
            float d = v_pre - TH;
            const bool sp = d > 0.f;
            if (sp) v_pre = d;
            {
                const u64 m = __ballot(sp);
                if (lane == 0) {
                    const u64 eh = ((u64)e) << 32;
                    st_u64(&ln0[(s * 2 + bi) * 8 + 2 * q],     eh | (m & 0xffffffffull));
                    st_u64(&ln0[(s * 2 + bi) * 8 + 2 * q + 1], eh | (m >> 32));
                }
            }
            // ---- FILL-1: first half of C(e-1) gather ----
            if (e >= 2)
                g1 = gatherseg(WpostAB, listS[parPrev][bi], 0, halfPrev, colB);
            __syncthreads();                                      // B1

            // ---- B: gather full s_pre list, v_a update, publish s_a ----
            const int cp = cntP_ls[bi];
            const float accB = gatherseg(WadB, listP[bi], 0, cp, colB);
            v_a = ALPHA * v_a + accB + bad;
            const float th = TH + BETA_A * ba;
            d = v_a - th;
            sa = d > 0.f;
            if (sa) v_a = d;
            ba = RHO * ba + (sa ? 1.f : 0.f);
            {
                const u64 m = __ballot(sa);
                if (lane == 0) {
                    const u64 eh = ((u64)e) << 32;
                    st_u64(&ln1[(s * 2 + bi) * 8 + 2 * q],     eh | (m & 0xffffffffull));
                    st_u64(&ln1[(s * 2 + bi) * 8 + 2 * q + 1], eh | (m >> 32));
                }
            }
            // ---- FILL-2: rest of C(e-1), finish v_post(e-1) ----
            if (e >= 2) {
                const float g2 = gatherseg(WpostAB, listS[parPrev][bi],
                                           halfPrev, cntPrev, colB);
                const int tp = (e - 2) / 3;
                const float ipost = IP_post[(tp * 128 + b) * 1024 + col];
                v_post = ALPHA * v_post + ipost + (g1 + g2);
                float dd = v_post - TH;
                const bool spost = dd > 0.f;
                if (spost) v_post = dd;
                if (e % 3 == 1) {   // ph=e-1 has k==2  (FIXED)
                    const u64 m = __ballot(spost);
                    if (lane == 0)
                        st_u64(&spkO[(tp * 128 + 2 * p + bi) * 16 + s * 4 + q], m);
                }
            }
            if (e == 96)
                out[32 * 128 * 256 + b * 1024 + col] = sa ? 1.f : 0.f;
            __syncthreads();                                      // B2

            // ---- next-A gather from fresh listS ----
            const int cs = cntS_ls[par][bi];
            halfPrev = (cs >> 1) & ~3;
            cntPrev  = cs;
            parPrev  = par;
            if (e < 96)
                accA = gatherseg(WpreAB, listS[par][bi], 0, cs, colB);
        }
        // ---- epilogue: v_post(96) (par(96) == 0) ----
        {
            const float ga = gatherseg(WpostAB, listS[0][bi], 0, halfPrev, colB);
            const float gb = gatherseg(WpostAB, listS[0][bi], halfPrev, cntPrev, colB);
            const float ipost = IP_post[(31 * 128 + b) * 1024 + col];
            v_post = ALPHA * v_post + ipost + (ga + gb);
            const float dd = v_post - TH;
            const u64 m = __ballot(dd > 0.f);
            if (lane == 0)
                st_u64(&spkO[(31 * 128 + 2 * p + bi) * 16 + s * 4 + q], m);
        }
    } else if (wid == 8) {
        // ================== comm wave: exchange-1 -> listP ==================
        const int cbi = lane >> 5, r = lane & 31, sl = r >> 3, h = r & 7;
        const int jbase = (sl * 256 + h * 32) << 12;
        for (int e = 1; e <= 96; ++e) {
            const int par = e & 1;
            const u64* ln0 = lines + ((p * 2 + par) * 2 + 0) * 64;
            u64 w; int gd = 0;
            do { w = ld_u64(&ln0[(sl * 2 + cbi) * 8 + h]); }
            while ((w >> 32) != (u64)e && ++gd < CAP);
            const u32 bits = (u32)w;
            const int pc = __popc(bits);
            int incl = pc;
            for (int dlt = 1; dlt < 32; dlt <<= 1) {
                const int v = __shfl_up(incl, dlt, 32);
                if ((lane & 31) >= dlt) incl += v;
            }
            int base = incl - pc;
            u32 m = bits;
            while (m) {
                const int bt = __builtin_ctz(m);
                m &= m - 1;
                listP[cbi][base++] = jbase + (bt << 12);
            }
            if ((lane & 31) == 31) cntP_ls[cbi] = incl;
            __syncthreads();                                      // B1
            __syncthreads();                                      // B2
        }
    } else {
        // ================== comm wave: exchange-2 -> listS[par] =============
        const int cbi = lane >> 5, r = lane & 31, sl = r >> 3, h = r & 7;
        const int jbase = (sl * 256 + h * 32) << 12;
        for (int e = 1; e <= 96; ++e) {
            const int par = e & 1;
            const u64* ln1 = lines + ((p * 2 + par) * 2 + 1) * 64;
            __syncthreads();                                      // B1
            u64 w; int gd = 0;
            do { w = ld_u64(&ln1[(sl * 2 + cbi) * 8 + h]); }
            while ((w >> 32) != (u64)e && ++gd < CAP);
            const u32 bits = (u32)w;
            const int pc = __popc(bits);
            int incl = pc;
            for (int dlt = 1; dlt < 32; dlt <<= 1) {
                const int v = __shfl_up(incl, dlt, 32);
                if ((lane & 31) >= dlt) incl += v;
            }
            int base = incl - pc;
            u32 m = bits;
            while (m) {
                const int bt = __builtin_ctz(m);
                m &= m - 1;
                listS[par][cbi][base++] = jbase + (bt << 12);
            }
            if ((lane & 31) == 31) cntS_ls[par][cbi] = incl;
            __syncthreads();                                      // B2
        }
    }
}

// ---------------------------------------------------------------------------
// Final output GEMM: o[r] = s_post[r] @ W_out.T + b_out, from spkO bitmaps.
// ---------------------------------------------------------------------------
__global__ __launch_bounds__(256) void out_gemm(const float* __restrict__ Wt_out,
                                                const float* __restrict__ b_out,
                                                const u64* __restrict__ spkO,
                                                float* __restrict__ out) {
    __shared__ u64 bmp[16];
    __shared__ int pc[16];
    __shared__ __align__(16) int list[1024];
    const int r = blockIdx.x, tid = threadIdx.x;
    if (tid < 16) {
        const u64 m = ld_u64(&spkO[r * 16 + tid]);
        bmp[tid] = m;
        pc[tid]  = __popcll(m);
    }
    __syncthreads();
    int total = 0;
#pragma unroll
    for (int w = 0; w < 16; ++w) total += pc[w];
    for (int j = tid; j < 1024; j += 256) {
        const int w = j >> 6, bit = j & 63;
        const u64 m = bmp[w];
        if ((m >> bit) & 1ull) {
            int base = __popcll(m & ((1ull << bit) - 1ull));
            for (int q2 = 0; q2 < w; ++q2) base += pc[q2];
            list[base] = j;
        }
    }
    __syncthreads();
    const float acc = gather_idx(Wt_out, list, total, tid);
    out[r * 256 + tid] = acc + b_out[tid];
}

// ---------------------------------------------------------------------------
extern "C" void kernel_launch(void* const* d_in, const int* in_sizes, int n_in,
                              void* d_out, int out_size, void* d_ws, size_t ws_size,
                              hipStream_t stream) {
    (void)in_sizes; (void)n_in; (void)out_size; (void)ws_size;
    const float* inp    = (const float*)d_in[0];
    const float* W_pre  = (const float*)d_in[1];
    const float* b_pre  = (const float*)d_in[2];
    const float* W_ad   = (const float*)d_in[3];
    const float* b_ad   = (const float*)d_in[4];
    const float* W_post = (const float*)d_in[5];
    const float* b_post = (const float*)d_in[6];
    const float* W_out  = (const float*)d_in[7];
    const float* b_out  = (const float*)d_in[8];

    char* base = (char*)d_ws;
    u64*  lines = (u64*)(base + 4096);               // 128 KB exchange lines
    u64*  spkO  = (u64*)(base + 147456);             // 512 KB
    float* ws      = (float*)(base + 1048576);
    float* Wt_pre  = ws;
    float* Wt_post = Wt_pre  + 1536 * 1024;
    float* Wt_ad   = Wt_post + 1536 * 1024;
    float* Wt_out  = Wt_ad   + 1024 * 1024;
    float* IP_pre  = Wt_out  + 1024 * 256;
    float* IP_post = IP_pre  + 4096 * 1024;

    hipMemsetAsync(base, 0, 4096 + 131072, stream);  // zero exchange lines

    transpose_k<<<dim3(48, 32), dim3(32, 8), 0, stream>>>(W_pre,  Wt_pre,  1024, 1536);
    transpose_k<<<dim3(48, 32), dim3(32, 8), 0, stream>>>(W_post, Wt_post, 1024, 1536);
    transpose_k<<<dim3(32, 32), dim3(32, 8), 0, stream>>>(W_ad,   Wt_ad,   1024, 1024);
    transpose_k<<<dim3(32, 8),  dim3(32, 8), 0, stream>>>(W_out,  Wt_out,  256,  1024);

    ip_gemm<<<dim3(4, 256), 256, 0, stream>>>(inp, Wt_pre,  b_pre,  IP_pre);
    ip_gemm<<<dim3(4, 256), 256, 0, stream>>>(inp, Wt_post, b_post, IP_post);

    rsnn_pc<<<256, 640, 0, stream>>>(Wt_pre, Wt_ad, Wt_post,
                                     IP_pre, IP_post, b_ad,
                                     lines, spkO, (float*)d_out);

    out_gemm<<<4096, 256, 0, stream>>>(Wt_out, b_out, spkO, (float*)d_out);
}